// Round 16
// baseline (436.824 us; speedup 1.0000x reference)
//
#include <hip/hip_runtime.h>
#include <math.h>

#define T_SEQ 2048
#define HID   4096
#define NH    32
#define NKV   8
#define HD    128
#define QCOLS (NH*HD)   // 4096
#define KCOLS (NKV*HD)  // 1024
#define KSTR  2048      // row stride of combined K|V buffer

typedef _Float16 f16;
typedef _Float16 f16x8 __attribute__((ext_vector_type(8)));
typedef _Float16 f16x4 __attribute__((ext_vector_type(4)));
typedef float f32x4 __attribute__((ext_vector_type(4)));

#define GLDS(g, l) __builtin_amdgcn_global_load_lds( \
    (const __attribute__((address_space(1))) void*)(g), \
    (__attribute__((address_space(3))) void*)(l), 16, 0, 0)

// ---------------- RoPE cos/sin table (llama3 scaling), f64 math ----------------
__global__ void rope_table(float* __restrict__ cosT, float* __restrict__ sinT) {
    int idx = blockIdx.x * blockDim.x + threadIdx.x;   // t*64 + i
    if (idx >= T_SEQ * 64) return;
    int t = idx >> 6, i = idx & 63;
    double inv = pow(500000.0, -(double)(2 * i) / 128.0);
    double wavelen = 6.283185307179586 / inv;
    const double lowwl = 8192.0, highwl = 2048.0;
    double scaled;
    if (wavelen > lowwl) {
        scaled = inv / 8.0;
    } else if (wavelen >= highwl) {
        double smooth = (8192.0 / wavelen - 1.0) / 3.0;
        scaled = (1.0 - smooth) * inv / 8.0 + smooth * inv;
    } else {
        scaled = inv;
    }
    float invf = (float)scaled;
    float phase = (float)t * invf;
    cosT[idx] = (float)cos((double)phase);
    sinT[idx] = (float)sin((double)phase);
}

// ---------------- fp32 -> f16 convert (row-major copy) ----------------
__global__ void convert_f32_f16(const float* __restrict__ in, f16* __restrict__ out, int n8) {
    int i = blockIdx.x * blockDim.x + threadIdx.x;
    if (i >= n8) return;
    float4 a = *(const float4*)(in + (size_t)i * 8);
    float4 b = *(const float4*)(in + (size_t)i * 8 + 4);
    f16x8 v = {(f16)a.x, (f16)a.y, (f16)a.z, (f16)a.w, (f16)b.x, (f16)b.y, (f16)b.z, (f16)b.w};
    *(f16x8*)(out + (size_t)i * 8) = v;
}

// ---------------- fp32 [rows][ld] col-slice -> f16 [cols][R] transpose ----------------
__global__ __launch_bounds__(256) void transpose_f32_to_f16(const float* __restrict__ in,
                                                            f16* __restrict__ out,
                                                            int R, int ld) {
    __shared__ f16 t[64][72];
    const int tid = threadIdx.x;
    const int r0 = blockIdx.y * 64, c0 = blockIdx.x * 64;
#pragma unroll
    for (int i = 0; i < 4; ++i) {
        int r = i * 16 + (tid >> 4), c4 = (tid & 15) * 4;
        float4 v = *(const float4*)(in + (size_t)(r0 + r) * ld + c0 + c4);
        t[r][c4 + 0] = (f16)v.x; t[r][c4 + 1] = (f16)v.y;
        t[r][c4 + 2] = (f16)v.z; t[r][c4 + 3] = (f16)v.w;
    }
    __syncthreads();
    int n = tid >> 2, j0 = (tid & 3) * 16;
    f16x8 a, b;
#pragma unroll
    for (int j = 0; j < 8; ++j) { a[j] = t[j0 + j][n]; b[j] = t[j0 + 8 + j][n]; }
    *(f16x8*)(out + (size_t)(c0 + n) * R + r0 + j0) = a;
    *(f16x8*)(out + (size_t)(c0 + n) * R + r0 + j0 + 8) = b;
}

// ---------------- f16 [*][ld] 64x64-tiled transpose ----------------
__global__ __launch_bounds__(256) void transpose_f16(const f16* __restrict__ in,
                                                     f16* __restrict__ out,
                                                     int R, int ld) {
    __shared__ f16 t[64][72];
    const int tid = threadIdx.x;
    const int r0 = blockIdx.y * 64, c0 = blockIdx.x * 64;
#pragma unroll
    for (int i = 0; i < 2; ++i) {
        int r = i * 32 + (tid >> 3), c8 = (tid & 7) * 8;
        f16x8 v = *(const f16x8*)(in + (size_t)(r0 + r) * ld + c0 + c8);
#pragma unroll
        for (int j = 0; j < 8; ++j) t[r][c8 + j] = v[j];
    }
    __syncthreads();
    int n = tid >> 2, j0 = (tid & 3) * 16;
    f16x8 a, b;
#pragma unroll
    for (int j = 0; j < 8; ++j) { a[j] = t[j0 + j][n]; b[j] = t[j0 + 8 + j][n]; }
    *(f16x8*)(out + (size_t)(c0 + n) * R + r0 + j0) = a;
    *(f16x8*)(out + (size_t)(c0 + n) * R + r0 + j0 + 8) = b;
}

// ---------------- f16 MFMA GEMM: C[M, ldc] = A[M,K] @ Bt[N,K]^T ----------------
// 128x128 tile, BK=64, double-buffered LDS, ONE barrier per K-step (verified R5).
template <typename OutT>
__global__ __launch_bounds__(256, 2) void gemm_f16(const f16* __restrict__ A,
                                                   const f16* __restrict__ Bt,
                                                   OutT* __restrict__ C,
                                                   int M, int ldc, int K) {
    __shared__ f16 As[2][128 * 64];
    __shared__ f16 Bs[2][128 * 64];
    const int tid = threadIdx.x;
    const int l = tid & 63;
    const int w = tid >> 6, wr = w >> 1, wc = w & 1;
    const int c16 = l & 15, g = l >> 4;
    const int m0 = blockIdx.y * 128, n0 = blockIdx.x * 128;

    f32x4 acc[4][4] = {};

    const int r_src = tid >> 3;                               // 0..31 (row mod 32)
    const int colswz = ((tid & 7) * 8) ^ ((r_src & 7) << 3);  // f16 units within BK=64
    const f16* gA = A + (size_t)(m0 + r_src) * K + colswz;
    const f16* gB = Bt + (size_t)(n0 + r_src) * K + colswz;

    auto stage = [&](f16* sA, f16* sB, int k0) {
#pragma unroll
        for (int i = 0; i < 4; ++i) {
            GLDS(gA + (size_t)(i * 32) * K + k0, sA + i * 2048 + tid * 8);
            GLDS(gB + (size_t)(i * 32) * K + k0, sB + i * 2048 + tid * 8);
        }
    };
    auto compute = [&](const f16* sA, const f16* sB) {
#pragma unroll
        for (int kk = 0; kk < 2; ++kk) {
            f16x8 af[4], bf[4];
#pragma unroll
            for (int mb = 0; mb < 4; ++mb) {
                int row = wr * 64 + mb * 16 + c16;
                af[mb] = *(const f16x8*)((const char*)sA + row * 128 +
                                         ((kk * 64 + g * 16) ^ ((row & 7) << 4)));
            }
#pragma unroll
            for (int nb = 0; nb < 4; ++nb) {
                int row = wc * 64 + nb * 16 + c16;
                bf[nb] = *(const f16x8*)((const char*)sB + row * 128 +
                                         ((kk * 64 + g * 16) ^ ((row & 7) << 4)));
            }
#pragma unroll
            for (int mb = 0; mb < 4; ++mb)
#pragma unroll
                for (int nb = 0; nb < 4; ++nb)
                    acc[mb][nb] = __builtin_amdgcn_mfma_f32_16x16x32_f16(af[mb], bf[nb], acc[mb][nb], 0, 0, 0);
        }
    };

    stage(As[0], Bs[0], 0);
    __syncthreads();
    int cur = 0;
    for (int k0 = 64; k0 < K; k0 += 64) {
        stage(As[cur ^ 1], Bs[cur ^ 1], k0);
        compute(As[cur], Bs[cur]);
        __syncthreads();
        cur ^= 1;
    }
    compute(As[cur], Bs[cur]);

#pragma unroll
    for (int mb = 0; mb < 4; ++mb)
#pragma unroll
        for (int nb = 0; nb < 4; ++nb)
#pragma unroll
            for (int r = 0; r < 4; ++r) {
                size_t row = m0 + wr * 64 + mb * 16 + g * 4 + r;
                C[row * ldc + n0 + wc * 64 + nb * 16 + c16] = (OutT)acc[mb][nb][r];
            }
}

// ---------------- RoPE apply in place on f16 (row stride parameterized) ----------------
__global__ void rope_apply_f16(f16* __restrict__ data, const float* __restrict__ cosT,
                               const float* __restrict__ sinT, int nheads, int stride) {
    int idx = blockIdx.x * blockDim.x + threadIdx.x;
    int lane = idx & 63;
    int row = idx >> 6;
    if (row >= T_SEQ * nheads) return;
    int t = row / nheads, h = row % nheads;
    f16* p = data + (size_t)t * stride + h * HD;
    float c = cosT[t * 64 + lane], s = sinT[t * 64 + lane];
    float x1 = (float)p[lane], x2 = (float)p[lane + 64];
    p[lane]      = (f16)(x1 * c - x2 * s);
    p[lane + 64] = (f16)(x2 * c + x1 * s);
}

// ---------------- MFMA flash attention v7 (r8 structure, V direct from L2) ----------------
// grid (16, NH); block bx handles qt = bx and qt = 31-bx (uniform 33 chunks).
// 4 waves; wave w owns q rows qt*64+w*16..+15. K DOUBLE-buffered via GLDS
// (pre-swizzled global source, linear LDS dest), ONE barrier per chunk.
// V is NOT staged: vtb is 4 MB (L2-resident); PV fragments read straight from
// global (m169 precedent: staging L2-fit data is pure overhead). This halves
// the per-chunk vmcnt drain and drops LDS to ~41.5 KB -> 3 blocks/CU.
// Fused Q-RoPE; lane-local online softmax (S^T = K @ Q^T); T13 defer-max.
__global__ __launch_bounds__(256, 3) void attn_f16(const f16* __restrict__ q,
                                                   const f16* __restrict__ k,
                                                   const f16* __restrict__ vt,
                                                   const float* __restrict__ cosT,
                                                   const float* __restrict__ sinT,
                                                   f16* __restrict__ outh) {
    __shared__ f16 Ks[2][64 * 128];   // rows of 256 B, XOR-swizzled content
    __shared__ f16 Ps[4][16 * 72];    // per-wave P, row stride 72 f16
    const int tid = threadIdx.x;
    const int l = tid & 63, w = tid >> 6;
    const int c16 = l & 15, g = l >> 4;
    const int h = blockIdx.y, kvh = h >> 2;
    const float SCALE = 0.08838834764831845f;

    const int kr = tid >> 4, kboff = (tid & 15) * 16;
    const char* kgb = (const char*)(k + kvh * HD);
    // per-lane V row pointer: row d = mb*16 + c16, key offset g*8 (+ ks2*32 + ch*64)
    const f16* vrow = vt + (size_t)(kvh * HD + c16) * T_SEQ + g * 8;

    auto stage = [&](int buf, int ch) {
#pragma unroll
        for (int i = 0; i < 4; ++i) {
            int r = i * 16 + kr;
            GLDS(kgb + (size_t)(ch * 64 + r) * (KSTR * 2) + (kboff ^ ((r & 7) << 4)),
                 (char*)Ks[buf] + i * 4096 + tid * 16);
        }
    };

    for (int pass = 0; pass < 2; ++pass) {
        const int qt = pass ? 31 - (int)blockIdx.x : (int)blockIdx.x;
        const int qrow = qt * 64 + w * 16 + c16;

        // ---- load Q + fused RoPE (pairs d, d+64 are qraw[ks], qraw[ks+2]) ----
        f16x8 qf[4];
        {
            const f16* qbase = q + (size_t)qrow * QCOLS + h * HD;
            f16x8 qraw[4];
#pragma unroll
            for (int ks = 0; ks < 4; ++ks) qraw[ks] = *(const f16x8*)(qbase + ks * 32 + g * 8);
            const float* cb = cosT + qrow * 64;
            const float* sb = sinT + qrow * 64;
#pragma unroll
            for (int ks = 0; ks < 2; ++ks) {
                int dbase = ks * 32 + g * 8;
                float4 c0 = *(const float4*)(cb + dbase);
                float4 c1 = *(const float4*)(cb + dbase + 4);
                float4 s0 = *(const float4*)(sb + dbase);
                float4 s1 = *(const float4*)(sb + dbase + 4);
                float cA[8] = {c0.x, c0.y, c0.z, c0.w, c1.x, c1.y, c1.z, c1.w};
                float sA[8] = {s0.x, s0.y, s0.z, s0.w, s1.x, s1.y, s1.z, s1.w};
#pragma unroll
                for (int j = 0; j < 8; ++j) {
                    float lo = (float)qraw[ks][j], hi = (float)qraw[ks + 2][j];
                    qf[ks][j]     = (f16)(lo * cA[j] - hi * sA[j]);
                    qf[ks + 2][j] = (f16)(hi * cA[j] + lo * sA[j]);
                }
            }
        }

        f32x4 o[8] = {};
        float mrun = -INFINITY, lrun = 0.f;

        stage(0, 0);
        __syncthreads();              // chunk 0 resident
        int cur = 0;
        for (int ch = 0; ch <= qt; ++ch) {
            if (ch < qt) stage(cur ^ 1, ch + 1);   // prefetch flies under compute

            // S^T = K @ Q^T : 4 key-blocks x 4 d-slices
            f32x4 st[4];
            __builtin_amdgcn_s_setprio(1);
#pragma unroll
            for (int kb = 0; kb < 4; ++kb) {
                f32x4 a = {};
#pragma unroll
                for (int ks = 0; ks < 4; ++ks) {
                    int row = kb * 16 + c16;
                    f16x8 kf = *(const f16x8*)((const char*)Ks[cur] + row * 256 +
                                               ((ks * 64 + g * 16) ^ ((row & 7) << 4)));
                    a = __builtin_amdgcn_mfma_f32_16x16x32_f16(kf, qf[ks], a, 0, 0, 0);
                }
                st[kb] = a;
            }
            __builtin_amdgcn_s_setprio(0);

            // scale + causal mask + online softmax (col q = c16 is lane-local)
            float p[16];
            float cmax = -INFINITY;
            const bool diag = (ch == qt);
#pragma unroll
            for (int kb = 0; kb < 4; ++kb)
#pragma unroll
                for (int r = 0; r < 4; ++r) {
                    float s = st[kb][r] * SCALE;
                    if (diag) {
                        int key = ch * 64 + kb * 16 + g * 4 + r;
                        if (key > qrow) s = -INFINITY;
                    }
                    p[kb * 4 + r] = s;
                    cmax = fmaxf(cmax, s);
                }
            cmax = fmaxf(cmax, __shfl_xor(cmax, 16));
            cmax = fmaxf(cmax, __shfl_xor(cmax, 32));

            // T13 defer-max: skip rescale while max grows < 8 (wave-uniform)
            float muse;
            if (__all(cmax <= mrun + 8.f)) {
                muse = mrun;
            } else {
                float mnew = fmaxf(mrun, cmax);
                float corr = __expf(mrun - mnew);
                lrun *= corr;
#pragma unroll
                for (int mb = 0; mb < 8; ++mb) o[mb] *= corr;
                mrun = mnew;
                muse = mnew;
            }
            float psum = 0.f;
#pragma unroll
            for (int i = 0; i < 16; ++i) { float e = __expf(p[i] - muse); p[i] = e; psum += e; }
            psum += __shfl_xor(psum, 16);
            psum += __shfl_xor(psum, 32);
            lrun += psum;

            // P -> per-wave LDS: row=q (c16), cols=keys
            f16* pw = Ps[w] + c16 * 72;
#pragma unroll
            for (int kb = 0; kb < 4; ++kb) {
                f16x4 q4 = {(f16)p[kb * 4], (f16)p[kb * 4 + 1], (f16)p[kb * 4 + 2], (f16)p[kb * 4 + 3]};
                *(f16x4*)(pw + kb * 16 + g * 4) = q4;
            }

            // O^T += Vt @ P^T : V fragments straight from global (L2-resident)
            __builtin_amdgcn_s_setprio(1);
#pragma unroll
            for (int ks2 = 0; ks2 < 2; ++ks2) {
                f16x8 pf = *(const f16x8*)(Ps[w] + c16 * 72 + ks2 * 32 + g * 8);
#pragma unroll
                for (int mb = 0; mb < 8; ++mb) {
                    f16x8 vf = *(const f16x8*)(vrow + (size_t)(mb * 16) * T_SEQ +
                                               ch * 64 + ks2 * 32);
                    o[mb] = __builtin_amdgcn_mfma_f32_16x16x32_f16(vf, pf, o[mb], 0, 0, 0);
                }
            }
            __builtin_amdgcn_s_setprio(0);

            __syncthreads();          // drains K prefetch; all waves done with cur
            cur ^= 1;
        }

        float invl = 1.f / lrun;
        f16* ob = outh + (size_t)qrow * QCOLS + h * HD;
#pragma unroll
        for (int mb = 0; mb < 8; ++mb) {
            f16x4 v = {(f16)(o[mb][0] * invl), (f16)(o[mb][1] * invl),
                       (f16)(o[mb][2] * invl), (f16)(o[mb][3] * invl)};
            *(f16x4*)(ob + mb * 16 + g * 4) = v;
        }
    }
}

// ---------------- host launch ----------------
// Workspace (77 MB high-water; round-0 proved ws_size >= 81 MB):
//   [0,1) cos/sin  [1,17) xh (->atth)  [17,33) qh  [33,41) kvh  [41,73) wT  [73,77) vtb
extern "C" void kernel_launch(void* const* d_in, const int* in_sizes, int n_in,
                              void* d_out, int out_size, void* d_ws, size_t ws_size,
                              hipStream_t stream) {
    const float* x  = (const float*)d_in[0];
    const float* wq = (const float*)d_in[1];
    const float* wk = (const float*)d_in[2];
    const float* wv = (const float*)d_in[3];
    const float* wo = (const float*)d_in[4];
    float* out = (float*)d_out;

    char* ws = (char*)d_ws;
    const size_t MB = 1024ULL * 1024ULL;
    float* cosT = (float*)(ws);
    float* sinT = (float*)(ws + 512 * 1024ULL);
    f16* xh   = (f16*)(ws + 1 * MB);
    f16* atth = xh;  // alias: xh dead after QKV GEMMs
    f16* qh   = (f16*)(ws + 17 * MB);
    f16* kvh  = (f16*)(ws + 33 * MB);
    f16* wT   = (f16*)(ws + 41 * MB);
    f16* vtb  = (f16*)(ws + 73 * MB);

    rope_table<<<dim3((T_SEQ * 64 + 255) / 256), dim3(256), 0, stream>>>(cosT, sinT);
    convert_f32_f16<<<dim3(T_SEQ * HID / 8 / 256), dim3(256), 0, stream>>>(x, xh, T_SEQ * HID / 8);

    // Q = x @ wq  (RoPE on Q is fused into attn)
    transpose_f32_to_f16<<<dim3(QCOLS / 64, HID / 64), dim3(256), 0, stream>>>(wq, wT, HID, QCOLS);
    gemm_f16<f16><<<dim3(QCOLS / 128, T_SEQ / 128), dim3(256), 0, stream>>>(
        xh, wT, qh, T_SEQ, QCOLS, HID);

    // K|V = x @ [wk|wv] into kvh[2048][2048]
    transpose_f32_to_f16<<<dim3(KCOLS / 64, HID / 64), dim3(256), 0, stream>>>(wk, wT, HID, KCOLS);
    transpose_f32_to_f16<<<dim3(KCOLS / 64, HID / 64), dim3(256), 0, stream>>>(
        wv, wT + (size_t)KCOLS * HID, HID, KCOLS);
    gemm_f16<f16><<<dim3(KSTR / 128, T_SEQ / 128), dim3(256), 0, stream>>>(
        xh, wT, kvh, T_SEQ, KSTR, HID);

    // RoPE on K only (Q fused into attn)
    rope_apply_f16<<<dim3(T_SEQ * NKV * 64 / 256), dim3(256), 0, stream>>>(
        kvh, cosT, sinT, NKV, KSTR);

    // vtb[d][t] = V^T from kvh cols 1024..2047
    transpose_f16<<<dim3(KCOLS / 64, T_SEQ / 64), dim3(256), 0, stream>>>(
        kvh + KCOLS, vtb, T_SEQ, KSTR);

    attn_f16<<<dim3(16, NH), dim3(256), 0, stream>>>(qh, kvh, vtb, cosT, sinT, atth);

    // out = atth @ wo
    transpose_f32_to_f16<<<dim3(HID / 64, QCOLS / 64), dim3(256), 0, stream>>>(wo, wT, QCOLS, HID);
    gemm_f16<float><<<dim3(HID / 128, T_SEQ / 128), dim3(256), 0, stream>>>(
        atth, wT, out, T_SEQ, HID, QCOLS);
}

// Round 17
// 347.331 us; speedup vs baseline: 1.2577x; 1.2577x over previous
//
#include <hip/hip_runtime.h>
#include <math.h>

#define T_SEQ 2048
#define HID   4096
#define NH    32
#define NKV   8
#define HD    128
#define QCOLS (NH*HD)   // 4096
#define KCOLS (NKV*HD)  // 1024
#define KSTR  2048      // row stride of combined K|V buffer
#define NTOT  (QCOLS + KSTR)  // 6144: merged QKV output columns

typedef _Float16 f16;
typedef _Float16 f16x8 __attribute__((ext_vector_type(8)));
typedef _Float16 f16x4 __attribute__((ext_vector_type(4)));
typedef float f32x4 __attribute__((ext_vector_type(4)));

#define GLDS(g, l) __builtin_amdgcn_global_load_lds( \
    (const __attribute__((address_space(1))) void*)(g), \
    (__attribute__((address_space(3))) void*)(l), 16, 0, 0)

// ---------------- RoPE cos/sin table (llama3 scaling), f64 math ----------------
__global__ void rope_table(float* __restrict__ cosT, float* __restrict__ sinT) {
    int idx = blockIdx.x * blockDim.x + threadIdx.x;   // t*64 + i
    if (idx >= T_SEQ * 64) return;
    int t = idx >> 6, i = idx & 63;
    double inv = pow(500000.0, -(double)(2 * i) / 128.0);
    double wavelen = 6.283185307179586 / inv;
    const double lowwl = 8192.0, highwl = 2048.0;
    double scaled;
    if (wavelen > lowwl) {
        scaled = inv / 8.0;
    } else if (wavelen >= highwl) {
        double smooth = (8192.0 / wavelen - 1.0) / 3.0;
        scaled = (1.0 - smooth) * inv / 8.0 + smooth * inv;
    } else {
        scaled = inv;
    }
    float invf = (float)scaled;
    float phase = (float)t * invf;
    cosT[idx] = (float)cos((double)phase);
    sinT[idx] = (float)sin((double)phase);
}

// ---------------- fp32 -> f16 convert (row-major copy) ----------------
__global__ void convert_f32_f16(const float* __restrict__ in, f16* __restrict__ out, int n8) {
    int i = blockIdx.x * blockDim.x + threadIdx.x;
    if (i >= n8) return;
    float4 a = *(const float4*)(in + (size_t)i * 8);
    float4 b = *(const float4*)(in + (size_t)i * 8 + 4);
    f16x8 v = {(f16)a.x, (f16)a.y, (f16)a.z, (f16)a.w, (f16)b.x, (f16)b.y, (f16)b.z, (f16)b.w};
    *(f16x8*)(out + (size_t)i * 8) = v;
}

// ---------------- fp32 [rows][ld] col-slice -> f16 [cols][R] transpose ----------------
__global__ __launch_bounds__(256) void transpose_f32_to_f16(const float* __restrict__ in,
                                                            f16* __restrict__ out,
                                                            int R, int ld) {
    __shared__ f16 t[64][72];
    const int tid = threadIdx.x;
    const int r0 = blockIdx.y * 64, c0 = blockIdx.x * 64;
#pragma unroll
    for (int i = 0; i < 4; ++i) {
        int r = i * 16 + (tid >> 4), c4 = (tid & 15) * 4;
        float4 v = *(const float4*)(in + (size_t)(r0 + r) * ld + c0 + c4);
        t[r][c4 + 0] = (f16)v.x; t[r][c4 + 1] = (f16)v.y;
        t[r][c4 + 2] = (f16)v.z; t[r][c4 + 3] = (f16)v.w;
    }
    __syncthreads();
    int n = tid >> 2, j0 = (tid & 3) * 16;
    f16x8 a, b;
#pragma unroll
    for (int j = 0; j < 8; ++j) { a[j] = t[j0 + j][n]; b[j] = t[j0 + 8 + j][n]; }
    *(f16x8*)(out + (size_t)(c0 + n) * R + r0 + j0) = a;
    *(f16x8*)(out + (size_t)(c0 + n) * R + r0 + j0 + 8) = b;
}

// ---------------- f16 [*][ld] 64x64-tiled transpose ----------------
__global__ __launch_bounds__(256) void transpose_f16(const f16* __restrict__ in,
                                                     f16* __restrict__ out,
                                                     int R, int ld) {
    __shared__ f16 t[64][72];
    const int tid = threadIdx.x;
    const int r0 = blockIdx.y * 64, c0 = blockIdx.x * 64;
#pragma unroll
    for (int i = 0; i < 2; ++i) {
        int r = i * 32 + (tid >> 3), c8 = (tid & 7) * 8;
        f16x8 v = *(const f16x8*)(in + (size_t)(r0 + r) * ld + c0 + c8);
#pragma unroll
        for (int j = 0; j < 8; ++j) t[r][c8 + j] = v[j];
    }
    __syncthreads();
    int n = tid >> 2, j0 = (tid & 3) * 16;
    f16x8 a, b;
#pragma unroll
    for (int j = 0; j < 8; ++j) { a[j] = t[j0 + j][n]; b[j] = t[j0 + 8 + j][n]; }
    *(f16x8*)(out + (size_t)(c0 + n) * R + r0 + j0) = a;
    *(f16x8*)(out + (size_t)(c0 + n) * R + r0 + j0 + 8) = b;
}

// ---------------- f16 MFMA GEMM: C[M, ldc] = A[M,K] @ Bt[N,K]^T ----------------
// 128x128 tile, BK=64, double-buffered LDS, ONE barrier per K-step (verified R5).
template <typename OutT>
__global__ __launch_bounds__(256, 2) void gemm_f16(const f16* __restrict__ A,
                                                   const f16* __restrict__ Bt,
                                                   OutT* __restrict__ C,
                                                   int M, int ldc, int K) {
    __shared__ f16 As[2][128 * 64];
    __shared__ f16 Bs[2][128 * 64];
    const int tid = threadIdx.x;
    const int l = tid & 63;
    const int w = tid >> 6, wr = w >> 1, wc = w & 1;
    const int c16 = l & 15, g = l >> 4;
    const int m0 = blockIdx.y * 128, n0 = blockIdx.x * 128;

    f32x4 acc[4][4] = {};

    const int r_src = tid >> 3;                               // 0..31 (row mod 32)
    const int colswz = ((tid & 7) * 8) ^ ((r_src & 7) << 3);  // f16 units within BK=64
    const f16* gA = A + (size_t)(m0 + r_src) * K + colswz;
    const f16* gB = Bt + (size_t)(n0 + r_src) * K + colswz;

    auto stage = [&](f16* sA, f16* sB, int k0) {
#pragma unroll
        for (int i = 0; i < 4; ++i) {
            GLDS(gA + (size_t)(i * 32) * K + k0, sA + i * 2048 + tid * 8);
            GLDS(gB + (size_t)(i * 32) * K + k0, sB + i * 2048 + tid * 8);
        }
    };
    auto compute = [&](const f16* sA, const f16* sB) {
#pragma unroll
        for (int kk = 0; kk < 2; ++kk) {
            f16x8 af[4], bf[4];
#pragma unroll
            for (int mb = 0; mb < 4; ++mb) {
                int row = wr * 64 + mb * 16 + c16;
                af[mb] = *(const f16x8*)((const char*)sA + row * 128 +
                                         ((kk * 64 + g * 16) ^ ((row & 7) << 4)));
            }
#pragma unroll
            for (int nb = 0; nb < 4; ++nb) {
                int row = wc * 64 + nb * 16 + c16;
                bf[nb] = *(const f16x8*)((const char*)sB + row * 128 +
                                         ((kk * 64 + g * 16) ^ ((row & 7) << 4)));
            }
#pragma unroll
            for (int mb = 0; mb < 4; ++mb)
#pragma unroll
                for (int nb = 0; nb < 4; ++nb)
                    acc[mb][nb] = __builtin_amdgcn_mfma_f32_16x16x32_f16(af[mb], bf[nb], acc[mb][nb], 0, 0, 0);
        }
    };

    stage(As[0], Bs[0], 0);
    __syncthreads();
    int cur = 0;
    for (int k0 = 64; k0 < K; k0 += 64) {
        stage(As[cur ^ 1], Bs[cur ^ 1], k0);
        compute(As[cur], Bs[cur]);
        __syncthreads();
        cur ^= 1;
    }
    compute(As[cur], Bs[cur]);

#pragma unroll
    for (int mb = 0; mb < 4; ++mb)
#pragma unroll
        for (int nb = 0; nb < 4; ++nb)
#pragma unroll
            for (int r = 0; r < 4; ++r) {
                size_t row = m0 + wr * 64 + mb * 16 + g * 4 + r;
                C[row * ldc + n0 + wc * 64 + nb * 16 + c16] = (OutT)acc[mb][nb][r];
            }
}

// ---------------- merged QKV GEMM: one launch over N = 4096(Q) | 2048(K|V) ----------------
// Same verified 128x128/BK=64/dbuf/one-barrier structure; block-uniform selection
// of B source (wqT or wkvT) and C destination (qh ldc=QCOLS, kvh ldc=KSTR).
__global__ __launch_bounds__(256, 2) void gemm_qkv(const f16* __restrict__ A,
                                                   const f16* __restrict__ Bq,
                                                   const f16* __restrict__ Bkv,
                                                   f16* __restrict__ Cq,
                                                   f16* __restrict__ Ckv,
                                                   int K) {
    __shared__ f16 As[2][128 * 64];
    __shared__ f16 Bs[2][128 * 64];
    const int tid = threadIdx.x;
    const int l = tid & 63;
    const int w = tid >> 6, wr = w >> 1, wc = w & 1;
    const int c16 = l & 15, g = l >> 4;
    const int m0 = blockIdx.y * 128, n0 = blockIdx.x * 128;

    // block-uniform source/dest selection
    const bool isQ = (n0 < QCOLS);
    const f16* Bbase = isQ ? (Bq + (size_t)n0 * K) : (Bkv + (size_t)(n0 - QCOLS) * K);
    f16* Cbase = isQ ? (Cq + n0) : (Ckv + (n0 - QCOLS));
    const int ldc = isQ ? QCOLS : KSTR;

    f32x4 acc[4][4] = {};

    const int r_src = tid >> 3;                               // 0..31 (row mod 32)
    const int colswz = ((tid & 7) * 8) ^ ((r_src & 7) << 3);  // f16 units within BK=64
    const f16* gA = A + (size_t)(m0 + r_src) * K + colswz;
    const f16* gB = Bbase + (size_t)r_src * K + colswz;

    auto stage = [&](f16* sA, f16* sB, int k0) {
#pragma unroll
        for (int i = 0; i < 4; ++i) {
            GLDS(gA + (size_t)(i * 32) * K + k0, sA + i * 2048 + tid * 8);
            GLDS(gB + (size_t)(i * 32) * K + k0, sB + i * 2048 + tid * 8);
        }
    };
    auto compute = [&](const f16* sA, const f16* sB) {
#pragma unroll
        for (int kk = 0; kk < 2; ++kk) {
            f16x8 af[4], bf[4];
#pragma unroll
            for (int mb = 0; mb < 4; ++mb) {
                int row = wr * 64 + mb * 16 + c16;
                af[mb] = *(const f16x8*)((const char*)sA + row * 128 +
                                         ((kk * 64 + g * 16) ^ ((row & 7) << 4)));
            }
#pragma unroll
            for (int nb = 0; nb < 4; ++nb) {
                int row = wc * 64 + nb * 16 + c16;
                bf[nb] = *(const f16x8*)((const char*)sB + row * 128 +
                                         ((kk * 64 + g * 16) ^ ((row & 7) << 4)));
            }
#pragma unroll
            for (int mb = 0; mb < 4; ++mb)
#pragma unroll
                for (int nb = 0; nb < 4; ++nb)
                    acc[mb][nb] = __builtin_amdgcn_mfma_f32_16x16x32_f16(af[mb], bf[nb], acc[mb][nb], 0, 0, 0);
        }
    };

    stage(As[0], Bs[0], 0);
    __syncthreads();
    int cur = 0;
    for (int k0 = 64; k0 < K; k0 += 64) {
        stage(As[cur ^ 1], Bs[cur ^ 1], k0);
        compute(As[cur], Bs[cur]);
        __syncthreads();
        cur ^= 1;
    }
    compute(As[cur], Bs[cur]);

#pragma unroll
    for (int mb = 0; mb < 4; ++mb)
#pragma unroll
        for (int nb = 0; nb < 4; ++nb)
#pragma unroll
            for (int r = 0; r < 4; ++r) {
                size_t row = m0 + wr * 64 + mb * 16 + g * 4 + r;
                Cbase[row * ldc + wc * 64 + nb * 16 + c16] = (f16)acc[mb][nb][r];
            }
}

// ---------------- RoPE apply in place on f16 (row stride parameterized) ----------------
__global__ void rope_apply_f16(f16* __restrict__ data, const float* __restrict__ cosT,
                               const float* __restrict__ sinT, int nheads, int stride) {
    int idx = blockIdx.x * blockDim.x + threadIdx.x;
    int lane = idx & 63;
    int row = idx >> 6;
    if (row >= T_SEQ * nheads) return;
    int t = row / nheads, h = row % nheads;
    f16* p = data + (size_t)t * stride + h * HD;
    float c = cosT[t * 64 + lane], s = sinT[t * 64 + lane];
    float x1 = (float)p[lane], x2 = (float)p[lane + 64];
    p[lane]      = (f16)(x1 * c - x2 * s);
    p[lane + 64] = (f16)(x2 * c + x1 * s);
}

// ---------------- MFMA flash attention (r8-verified, 87.4 us) ----------------
// grid (16, NH); block bx handles qt = bx and qt = 31-bx (uniform 33 chunks).
// 4 waves; wave w owns q rows qt*64+w*16..+15. K/V DOUBLE-buffered via GLDS
// (pre-swizzled global source, linear LDS dest), ONE barrier per chunk.
// Fused Q-RoPE; lane-local online softmax (S^T = K @ Q^T); T13 defer-max.
__global__ __launch_bounds__(256, 2) void attn_f16(const f16* __restrict__ q,
                                                   const f16* __restrict__ k,
                                                   const f16* __restrict__ vt,
                                                   const float* __restrict__ cosT,
                                                   const float* __restrict__ sinT,
                                                   f16* __restrict__ outh) {
    __shared__ f16 Ks[2][64 * 128];   // rows of 256 B, XOR-swizzled content
    __shared__ f16 Vs[2][128 * 64];   // Vt rows of 128 B, XOR-swizzled content
    __shared__ f16 Ps[4][16 * 72];    // per-wave P, row stride 72 f16
    const int tid = threadIdx.x;
    const int l = tid & 63, w = tid >> 6;
    const int c16 = l & 15, g = l >> 4;
    const int h = blockIdx.y, kvh = h >> 2;
    const float SCALE = 0.08838834764831845f;

    const int kr = tid >> 4, kboff = (tid & 15) * 16;
    const int vr = tid >> 3, vboff = (tid & 7) * 16;
    const char* kgb = (const char*)(k + kvh * HD);
    const char* vgb = (const char*)(vt + (size_t)(kvh * HD) * T_SEQ);

    auto stage = [&](int buf, int ch) {
#pragma unroll
        for (int i = 0; i < 4; ++i) {
            int r = i * 16 + kr;
            GLDS(kgb + (size_t)(ch * 64 + r) * (KSTR * 2) + (kboff ^ ((r & 7) << 4)),
                 (char*)Ks[buf] + i * 4096 + tid * 16);
            int d = i * 32 + vr;
            GLDS(vgb + (size_t)d * (T_SEQ * 2) + (size_t)(ch * 64) * 2 + (vboff ^ ((d & 7) << 4)),
                 (char*)Vs[buf] + i * 4096 + tid * 16);
        }
    };

    for (int pass = 0; pass < 2; ++pass) {
        const int qt = pass ? 31 - (int)blockIdx.x : (int)blockIdx.x;
        const int qrow = qt * 64 + w * 16 + c16;

        // ---- load Q + fused RoPE (pairs d, d+64 are qraw[ks], qraw[ks+2]) ----
        f16x8 qf[4];
        {
            const f16* qbase = q + (size_t)qrow * QCOLS + h * HD;
            f16x8 qraw[4];
#pragma unroll
            for (int ks = 0; ks < 4; ++ks) qraw[ks] = *(const f16x8*)(qbase + ks * 32 + g * 8);
            const float* cb = cosT + qrow * 64;
            const float* sb = sinT + qrow * 64;
#pragma unroll
            for (int ks = 0; ks < 2; ++ks) {
                int dbase = ks * 32 + g * 8;
                float4 c0 = *(const float4*)(cb + dbase);
                float4 c1 = *(const float4*)(cb + dbase + 4);
                float4 s0 = *(const float4*)(sb + dbase);
                float4 s1 = *(const float4*)(sb + dbase + 4);
                float cA[8] = {c0.x, c0.y, c0.z, c0.w, c1.x, c1.y, c1.z, c1.w};
                float sA[8] = {s0.x, s0.y, s0.z, s0.w, s1.x, s1.y, s1.z, s1.w};
#pragma unroll
                for (int j = 0; j < 8; ++j) {
                    float lo = (float)qraw[ks][j], hi = (float)qraw[ks + 2][j];
                    qf[ks][j]     = (f16)(lo * cA[j] - hi * sA[j]);
                    qf[ks + 2][j] = (f16)(hi * cA[j] + lo * sA[j]);
                }
            }
        }

        f32x4 o[8] = {};
        float mrun = -INFINITY, lrun = 0.f;

        stage(0, 0);
        __syncthreads();              // chunk 0 resident
        int cur = 0;
        for (int ch = 0; ch <= qt; ++ch) {
            if (ch < qt) stage(cur ^ 1, ch + 1);   // prefetch flies under compute

            // S^T = K @ Q^T : 4 key-blocks x 4 d-slices
            f32x4 st[4];
            __builtin_amdgcn_s_setprio(1);
#pragma unroll
            for (int kb = 0; kb < 4; ++kb) {
                f32x4 a = {};
#pragma unroll
                for (int ks = 0; ks < 4; ++ks) {
                    int row = kb * 16 + c16;
                    f16x8 kf = *(const f16x8*)((const char*)Ks[cur] + row * 256 +
                                               ((ks * 64 + g * 16) ^ ((row & 7) << 4)));
                    a = __builtin_amdgcn_mfma_f32_16x16x32_f16(kf, qf[ks], a, 0, 0, 0);
                }
                st[kb] = a;
            }
            __builtin_amdgcn_s_setprio(0);

            // scale + causal mask + online softmax (col q = c16 is lane-local)
            float p[16];
            float cmax = -INFINITY;
            const bool diag = (ch == qt);
#pragma unroll
            for (int kb = 0; kb < 4; ++kb)
#pragma unroll
                for (int r = 0; r < 4; ++r) {
                    float s = st[kb][r] * SCALE;
                    if (diag) {
                        int key = ch * 64 + kb * 16 + g * 4 + r;
                        if (key > qrow) s = -INFINITY;
                    }
                    p[kb * 4 + r] = s;
                    cmax = fmaxf(cmax, s);
                }
            cmax = fmaxf(cmax, __shfl_xor(cmax, 16));
            cmax = fmaxf(cmax, __shfl_xor(cmax, 32));

            // T13 defer-max: skip rescale while max grows < 8 (wave-uniform)
            float muse;
            if (__all(cmax <= mrun + 8.f)) {
                muse = mrun;
            } else {
                float mnew = fmaxf(mrun, cmax);
                float corr = __expf(mrun - mnew);
                lrun *= corr;
#pragma unroll
                for (int mb = 0; mb < 8; ++mb) o[mb] *= corr;
                mrun = mnew;
                muse = mnew;
            }
            float psum = 0.f;
#pragma unroll
            for (int i = 0; i < 16; ++i) { float e = __expf(p[i] - muse); p[i] = e; psum += e; }
            psum += __shfl_xor(psum, 16);
            psum += __shfl_xor(psum, 32);
            lrun += psum;

            // P -> per-wave LDS: row=q (c16), cols=keys
            f16* pw = Ps[w] + c16 * 72;
#pragma unroll
            for (int kb = 0; kb < 4; ++kb) {
                f16x4 q4 = {(f16)p[kb * 4], (f16)p[kb * 4 + 1], (f16)p[kb * 4 + 2], (f16)p[kb * 4 + 3]};
                *(f16x4*)(pw + kb * 16 + g * 4) = q4;
            }

            // O^T += Vt @ P^T : 8 d-blocks x 2 key-slices
            __builtin_amdgcn_s_setprio(1);
#pragma unroll
            for (int ks2 = 0; ks2 < 2; ++ks2) {
                f16x8 pf = *(const f16x8*)(Ps[w] + c16 * 72 + ks2 * 32 + g * 8);
#pragma unroll
                for (int mb = 0; mb < 8; ++mb) {
                    int row = mb * 16 + c16;
                    f16x8 vf = *(const f16x8*)((const char*)Vs[cur] + row * 128 +
                                               ((ks2 * 64 + g * 16) ^ ((row & 7) << 4)));
                    o[mb] = __builtin_amdgcn_mfma_f32_16x16x32_f16(vf, pf, o[mb], 0, 0, 0);
                }
            }
            __builtin_amdgcn_s_setprio(0);

            __syncthreads();          // drains prefetch; all waves done with cur
            cur ^= 1;
        }

        float invl = 1.f / lrun;
        f16* ob = outh + (size_t)qrow * QCOLS + h * HD;
#pragma unroll
        for (int mb = 0; mb < 8; ++mb) {
            f16x4 v = {(f16)(o[mb][0] * invl), (f16)(o[mb][1] * invl),
                       (f16)(o[mb][2] * invl), (f16)(o[mb][3] * invl)};
            *(f16x4*)(ob + mb * 16 + g * 4) = v;
        }
    }
}

// ---------------- host launch ----------------
// Workspace (77 MB high-water; round-0 proved ws_size >= 81 MB):
//   [0,1) cos/sin  [1,17) xh (->atth)  [17,33) qh  [33,41) kvh
//   [41,53) wkvT (dead after QKV GEMM) / [41,73) woT (after attn)  [73,77) vtb
// wqT (32 MB) lives in d_out — dead before the out-GEMM overwrites d_out.
extern "C" void kernel_launch(void* const* d_in, const int* in_sizes, int n_in,
                              void* d_out, int out_size, void* d_ws, size_t ws_size,
                              hipStream_t stream) {
    const float* x  = (const float*)d_in[0];
    const float* wq = (const float*)d_in[1];
    const float* wk = (const float*)d_in[2];
    const float* wv = (const float*)d_in[3];
    const float* wo = (const float*)d_in[4];
    float* out = (float*)d_out;

    char* ws = (char*)d_ws;
    const size_t MB = 1024ULL * 1024ULL;
    float* cosT = (float*)(ws);
    float* sinT = (float*)(ws + 512 * 1024ULL);
    f16* xh   = (f16*)(ws + 1 * MB);
    f16* atth = xh;  // alias: xh dead after QKV GEMM
    f16* qh   = (f16*)(ws + 17 * MB);
    f16* kvh  = (f16*)(ws + 33 * MB);
    f16* wkvT = (f16*)(ws + 41 * MB);   // [2048][4096] f16 = 16 MB
    f16* woT  = (f16*)(ws + 41 * MB);   // [4096][4096] f16 = 32 MB (after attn)
    f16* vtb  = (f16*)(ws + 73 * MB);
    f16* wqT  = (f16*)d_out;            // 32 MB scratch, dead before out-GEMM

    rope_table<<<dim3((T_SEQ * 64 + 255) / 256), dim3(256), 0, stream>>>(cosT, sinT);
    convert_f32_f16<<<dim3(T_SEQ * HID / 8 / 256), dim3(256), 0, stream>>>(x, xh, T_SEQ * HID / 8);

    // transpose weights: wq -> wqT (d_out), wk|wv -> wkvT
    transpose_f32_to_f16<<<dim3(QCOLS / 64, HID / 64), dim3(256), 0, stream>>>(wq, wqT, HID, QCOLS);
    transpose_f32_to_f16<<<dim3(KCOLS / 64, HID / 64), dim3(256), 0, stream>>>(wk, wkvT, HID, KCOLS);
    transpose_f32_to_f16<<<dim3(KCOLS / 64, HID / 64), dim3(256), 0, stream>>>(
        wv, wkvT + (size_t)KCOLS * HID, HID, KCOLS);

    // merged Q|K|V GEMM: one 768-block launch (N = 4096 | 2048)
    gemm_qkv<<<dim3(NTOT / 128, T_SEQ / 128), dim3(256), 0, stream>>>(
        xh, wqT, wkvT, qh, kvh, HID);

    // RoPE on K only (Q fused into attn)
    rope_apply_f16<<<dim3(T_SEQ * NKV * 64 / 256), dim3(256), 0, stream>>>(
        kvh, cosT, sinT, NKV, KSTR);

    // vtb[d][t] = V^T from kvh cols 1024..2047
    transpose_f16<<<dim3(KCOLS / 64, T_SEQ / 64), dim3(256), 0, stream>>>(
        kvh + KCOLS, vtb, T_SEQ, KSTR);

    attn_f16<<<dim3(16, NH), dim3(256), 0, stream>>>(qh, kvh, vtb, cosT, sinT, atth);

    // out = atth @ wo
    transpose_f32_to_f16<<<dim3(HID / 64, QCOLS / 64), dim3(256), 0, stream>>>(wo, woT, QCOLS, HID);
    gemm_f16<float><<<dim3(HID / 128, T_SEQ / 128), dim3(256), 0, stream>>>(
        atth, woT, out, T_SEQ, HID, QCOLS);
}

// Round 18
// 347.141 us; speedup vs baseline: 1.2583x; 1.0005x over previous
//
#include <hip/hip_runtime.h>
#include <math.h>

#define T_SEQ 2048
#define HID   4096
#define NH    32
#define NKV   8
#define HD    128
#define QCOLS (NH*HD)   // 4096
#define KCOLS (NKV*HD)  // 1024
#define KSTR  2048      // row stride of combined K|V buffer
#define NTOT  (QCOLS + KSTR)  // 6144: merged QKV output columns

typedef _Float16 f16;
typedef _Float16 f16x8 __attribute__((ext_vector_type(8)));
typedef _Float16 f16x4 __attribute__((ext_vector_type(4)));
typedef float f32x4 __attribute__((ext_vector_type(4)));

#define GLDS(g, l) __builtin_amdgcn_global_load_lds( \
    (const __attribute__((address_space(1))) void*)(g), \
    (__attribute__((address_space(3))) void*)(l), 16, 0, 0)

// ---------------- RoPE cos/sin table (llama3 scaling), f64 math ----------------
__global__ void rope_table(float* __restrict__ cosT, float* __restrict__ sinT) {
    int idx = blockIdx.x * blockDim.x + threadIdx.x;   // t*64 + i
    if (idx >= T_SEQ * 64) return;
    int t = idx >> 6, i = idx & 63;
    double inv = pow(500000.0, -(double)(2 * i) / 128.0);
    double wavelen = 6.283185307179586 / inv;
    const double lowwl = 8192.0, highwl = 2048.0;
    double scaled;
    if (wavelen > lowwl) {
        scaled = inv / 8.0;
    } else if (wavelen >= highwl) {
        double smooth = (8192.0 / wavelen - 1.0) / 3.0;
        scaled = (1.0 - smooth) * inv / 8.0 + smooth * inv;
    } else {
        scaled = inv;
    }
    float invf = (float)scaled;
    float phase = (float)t * invf;
    cosT[idx] = (float)cos((double)phase);
    sinT[idx] = (float)sin((double)phase);
}

// ---------------- fp32 -> f16 convert (row-major copy) ----------------
__global__ void convert_f32_f16(const float* __restrict__ in, f16* __restrict__ out, int n8) {
    int i = blockIdx.x * blockDim.x + threadIdx.x;
    if (i >= n8) return;
    float4 a = *(const float4*)(in + (size_t)i * 8);
    float4 b = *(const float4*)(in + (size_t)i * 8 + 4);
    f16x8 v = {(f16)a.x, (f16)a.y, (f16)a.z, (f16)a.w, (f16)b.x, (f16)b.y, (f16)b.z, (f16)b.w};
    *(f16x8*)(out + (size_t)i * 8) = v;
}

// ---------------- fp32 [rows][ld] col-slice -> f16 [cols][R] transpose ----------------
__global__ __launch_bounds__(256) void transpose_f32_to_f16(const float* __restrict__ in,
                                                            f16* __restrict__ out,
                                                            int R, int ld) {
    __shared__ f16 t[64][72];
    const int tid = threadIdx.x;
    const int r0 = blockIdx.y * 64, c0 = blockIdx.x * 64;
#pragma unroll
    for (int i = 0; i < 4; ++i) {
        int r = i * 16 + (tid >> 4), c4 = (tid & 15) * 4;
        float4 v = *(const float4*)(in + (size_t)(r0 + r) * ld + c0 + c4);
        t[r][c4 + 0] = (f16)v.x; t[r][c4 + 1] = (f16)v.y;
        t[r][c4 + 2] = (f16)v.z; t[r][c4 + 3] = (f16)v.w;
    }
    __syncthreads();
    int n = tid >> 2, j0 = (tid & 3) * 16;
    f16x8 a, b;
#pragma unroll
    for (int j = 0; j < 8; ++j) { a[j] = t[j0 + j][n]; b[j] = t[j0 + 8 + j][n]; }
    *(f16x8*)(out + (size_t)(c0 + n) * R + r0 + j0) = a;
    *(f16x8*)(out + (size_t)(c0 + n) * R + r0 + j0 + 8) = b;
}

// ---------------- f16 [*][ld] 64x64-tiled transpose ----------------
__global__ __launch_bounds__(256) void transpose_f16(const f16* __restrict__ in,
                                                     f16* __restrict__ out,
                                                     int R, int ld) {
    __shared__ f16 t[64][72];
    const int tid = threadIdx.x;
    const int r0 = blockIdx.y * 64, c0 = blockIdx.x * 64;
#pragma unroll
    for (int i = 0; i < 2; ++i) {
        int r = i * 32 + (tid >> 3), c8 = (tid & 7) * 8;
        f16x8 v = *(const f16x8*)(in + (size_t)(r0 + r) * ld + c0 + c8);
#pragma unroll
        for (int j = 0; j < 8; ++j) t[r][c8 + j] = v[j];
    }
    __syncthreads();
    int n = tid >> 2, j0 = (tid & 3) * 16;
    f16x8 a, b;
#pragma unroll
    for (int j = 0; j < 8; ++j) { a[j] = t[j0 + j][n]; b[j] = t[j0 + 8 + j][n]; }
    *(f16x8*)(out + (size_t)(c0 + n) * R + r0 + j0) = a;
    *(f16x8*)(out + (size_t)(c0 + n) * R + r0 + j0 + 8) = b;
}

// ---------------- f16 MFMA GEMM: C[M, ldc] = A[M,K] @ Bt[N,K]^T ----------------
// 128x128 tile, BK=64, double-buffered LDS, ONE barrier per K-step (verified R5).
template <typename OutT>
__global__ __launch_bounds__(256, 2) void gemm_f16(const f16* __restrict__ A,
                                                   const f16* __restrict__ Bt,
                                                   OutT* __restrict__ C,
                                                   int M, int ldc, int K) {
    __shared__ f16 As[2][128 * 64];
    __shared__ f16 Bs[2][128 * 64];
    const int tid = threadIdx.x;
    const int l = tid & 63;
    const int w = tid >> 6, wr = w >> 1, wc = w & 1;
    const int c16 = l & 15, g = l >> 4;
    const int m0 = blockIdx.y * 128, n0 = blockIdx.x * 128;

    f32x4 acc[4][4] = {};

    const int r_src = tid >> 3;                               // 0..31 (row mod 32)
    const int colswz = ((tid & 7) * 8) ^ ((r_src & 7) << 3);  // f16 units within BK=64
    const f16* gA = A + (size_t)(m0 + r_src) * K + colswz;
    const f16* gB = Bt + (size_t)(n0 + r_src) * K + colswz;

    auto stage = [&](f16* sA, f16* sB, int k0) {
#pragma unroll
        for (int i = 0; i < 4; ++i) {
            GLDS(gA + (size_t)(i * 32) * K + k0, sA + i * 2048 + tid * 8);
            GLDS(gB + (size_t)(i * 32) * K + k0, sB + i * 2048 + tid * 8);
        }
    };
    auto compute = [&](const f16* sA, const f16* sB) {
#pragma unroll
        for (int kk = 0; kk < 2; ++kk) {
            f16x8 af[4], bf[4];
#pragma unroll
            for (int mb = 0; mb < 4; ++mb) {
                int row = wr * 64 + mb * 16 + c16;
                af[mb] = *(const f16x8*)((const char*)sA + row * 128 +
                                         ((kk * 64 + g * 16) ^ ((row & 7) << 4)));
            }
#pragma unroll
            for (int nb = 0; nb < 4; ++nb) {
                int row = wc * 64 + nb * 16 + c16;
                bf[nb] = *(const f16x8*)((const char*)sB + row * 128 +
                                         ((kk * 64 + g * 16) ^ ((row & 7) << 4)));
            }
#pragma unroll
            for (int mb = 0; mb < 4; ++mb)
#pragma unroll
                for (int nb = 0; nb < 4; ++nb)
                    acc[mb][nb] = __builtin_amdgcn_mfma_f32_16x16x32_f16(af[mb], bf[nb], acc[mb][nb], 0, 0, 0);
        }
    };

    stage(As[0], Bs[0], 0);
    __syncthreads();
    int cur = 0;
    for (int k0 = 64; k0 < K; k0 += 64) {
        stage(As[cur ^ 1], Bs[cur ^ 1], k0);
        compute(As[cur], Bs[cur]);
        __syncthreads();
        cur ^= 1;
    }
    compute(As[cur], Bs[cur]);

#pragma unroll
    for (int mb = 0; mb < 4; ++mb)
#pragma unroll
        for (int nb = 0; nb < 4; ++nb)
#pragma unroll
            for (int r = 0; r < 4; ++r) {
                size_t row = m0 + wr * 64 + mb * 16 + g * 4 + r;
                C[row * ldc + n0 + wc * 64 + nb * 16 + c16] = (OutT)acc[mb][nb][r];
            }
}

// ---------------- merged QKV GEMM: one launch over N = 4096(Q) | 2048(K|V) ----------------
__global__ __launch_bounds__(256, 2) void gemm_qkv(const f16* __restrict__ A,
                                                   const f16* __restrict__ Bq,
                                                   const f16* __restrict__ Bkv,
                                                   f16* __restrict__ Cq,
                                                   f16* __restrict__ Ckv,
                                                   int K) {
    __shared__ f16 As[2][128 * 64];
    __shared__ f16 Bs[2][128 * 64];
    const int tid = threadIdx.x;
    const int l = tid & 63;
    const int w = tid >> 6, wr = w >> 1, wc = w & 1;
    const int c16 = l & 15, g = l >> 4;
    const int m0 = blockIdx.y * 128, n0 = blockIdx.x * 128;

    const bool isQ = (n0 < QCOLS);
    const f16* Bbase = isQ ? (Bq + (size_t)n0 * K) : (Bkv + (size_t)(n0 - QCOLS) * K);
    f16* Cbase = isQ ? (Cq + n0) : (Ckv + (n0 - QCOLS));
    const int ldc = isQ ? QCOLS : KSTR;

    f32x4 acc[4][4] = {};

    const int r_src = tid >> 3;
    const int colswz = ((tid & 7) * 8) ^ ((r_src & 7) << 3);
    const f16* gA = A + (size_t)(m0 + r_src) * K + colswz;
    const f16* gB = Bbase + (size_t)r_src * K + colswz;

    auto stage = [&](f16* sA, f16* sB, int k0) {
#pragma unroll
        for (int i = 0; i < 4; ++i) {
            GLDS(gA + (size_t)(i * 32) * K + k0, sA + i * 2048 + tid * 8);
            GLDS(gB + (size_t)(i * 32) * K + k0, sB + i * 2048 + tid * 8);
        }
    };
    auto compute = [&](const f16* sA, const f16* sB) {
#pragma unroll
        for (int kk = 0; kk < 2; ++kk) {
            f16x8 af[4], bf[4];
#pragma unroll
            for (int mb = 0; mb < 4; ++mb) {
                int row = wr * 64 + mb * 16 + c16;
                af[mb] = *(const f16x8*)((const char*)sA + row * 128 +
                                         ((kk * 64 + g * 16) ^ ((row & 7) << 4)));
            }
#pragma unroll
            for (int nb = 0; nb < 4; ++nb) {
                int row = wc * 64 + nb * 16 + c16;
                bf[nb] = *(const f16x8*)((const char*)sB + row * 128 +
                                         ((kk * 64 + g * 16) ^ ((row & 7) << 4)));
            }
#pragma unroll
            for (int mb = 0; mb < 4; ++mb)
#pragma unroll
                for (int nb = 0; nb < 4; ++nb)
                    acc[mb][nb] = __builtin_amdgcn_mfma_f32_16x16x32_f16(af[mb], bf[nb], acc[mb][nb], 0, 0, 0);
        }
    };

    stage(As[0], Bs[0], 0);
    __syncthreads();
    int cur = 0;
    for (int k0 = 64; k0 < K; k0 += 64) {
        stage(As[cur ^ 1], Bs[cur ^ 1], k0);
        compute(As[cur], Bs[cur]);
        __syncthreads();
        cur ^= 1;
    }
    compute(As[cur], Bs[cur]);

#pragma unroll
    for (int mb = 0; mb < 4; ++mb)
#pragma unroll
        for (int nb = 0; nb < 4; ++nb)
#pragma unroll
            for (int r = 0; r < 4; ++r) {
                size_t row = m0 + wr * 64 + mb * 16 + g * 4 + r;
                Cbase[row * ldc + wc * 64 + nb * 16 + c16] = (f16)acc[mb][nb][r];
            }
}

// ---------------- RoPE apply in place on f16 (row stride parameterized) ----------------
__global__ void rope_apply_f16(f16* __restrict__ data, const float* __restrict__ cosT,
                               const float* __restrict__ sinT, int nheads, int stride) {
    int idx = blockIdx.x * blockDim.x + threadIdx.x;
    int lane = idx & 63;
    int row = idx >> 6;
    if (row >= T_SEQ * nheads) return;
    int t = row / nheads, h = row % nheads;
    f16* p = data + (size_t)t * stride + h * HD;
    float c = cosT[t * 64 + lane], s = sinT[t * 64 + lane];
    float x1 = (float)p[lane], x2 = (float)p[lane + 64];
    p[lane]      = (f16)(x1 * c - x2 * s);
    p[lane + 64] = (f16)(x2 * c + x1 * s);
}

// ---------------- MFMA flash attention v8 (r7 staging + r8 fusions) ----------------
// grid (16, NH); block bx handles qt = bx and qt = 31-bx (uniform 33 chunks).
// 4 waves; wave w owns q rows qt*64+w*16..+15. K/V SINGLE-buffered via GLDS
// (pre-swizzled global source, linear LDS dest), TWO barriers per chunk —
// the r7-measured-best staging (grid-limited 2 blocks/CU phase-interleave).
// Fused Q-RoPE; lane-local online softmax (S^T = K @ Q^T); T13 defer-max.
__global__ __launch_bounds__(256, 3) void attn_f16(const f16* __restrict__ q,
                                                   const f16* __restrict__ k,
                                                   const f16* __restrict__ vt,
                                                   const float* __restrict__ cosT,
                                                   const float* __restrict__ sinT,
                                                   f16* __restrict__ outh) {
    __shared__ f16 Ks[64 * 128];   // rows of 256 B, XOR-swizzled content
    __shared__ f16 Vs[128 * 64];   // Vt rows of 128 B, XOR-swizzled content
    __shared__ f16 Ps[4][16 * 72]; // per-wave P, row stride 72 f16
    const int tid = threadIdx.x;
    const int l = tid & 63, w = tid >> 6;
    const int c16 = l & 15, g = l >> 4;
    const int h = blockIdx.y, kvh = h >> 2;
    const float SCALE = 0.08838834764831845f;

    const int kr = tid >> 4, kboff = (tid & 15) * 16;
    const int vr = tid >> 3, vboff = (tid & 7) * 16;
    const char* kgb = (const char*)(k + kvh * HD);
    const char* vgb = (const char*)(vt + (size_t)(kvh * HD) * T_SEQ);

    for (int pass = 0; pass < 2; ++pass) {
        const int qt = pass ? 31 - (int)blockIdx.x : (int)blockIdx.x;
        const int qrow = qt * 64 + w * 16 + c16;

        // ---- load Q + fused RoPE (pairs d, d+64 are qraw[ks], qraw[ks+2]) ----
        f16x8 qf[4];
        {
            const f16* qbase = q + (size_t)qrow * QCOLS + h * HD;
            f16x8 qraw[4];
#pragma unroll
            for (int ks = 0; ks < 4; ++ks) qraw[ks] = *(const f16x8*)(qbase + ks * 32 + g * 8);
            const float* cb = cosT + qrow * 64;
            const float* sb = sinT + qrow * 64;
#pragma unroll
            for (int ks = 0; ks < 2; ++ks) {
                int dbase = ks * 32 + g * 8;
                float4 c0 = *(const float4*)(cb + dbase);
                float4 c1 = *(const float4*)(cb + dbase + 4);
                float4 s0 = *(const float4*)(sb + dbase);
                float4 s1 = *(const float4*)(sb + dbase + 4);
                float cA[8] = {c0.x, c0.y, c0.z, c0.w, c1.x, c1.y, c1.z, c1.w};
                float sA[8] = {s0.x, s0.y, s0.z, s0.w, s1.x, s1.y, s1.z, s1.w};
#pragma unroll
                for (int j = 0; j < 8; ++j) {
                    float lo = (float)qraw[ks][j], hi = (float)qraw[ks + 2][j];
                    qf[ks][j]     = (f16)(lo * cA[j] - hi * sA[j]);
                    qf[ks + 2][j] = (f16)(hi * cA[j] + lo * sA[j]);
                }
            }
        }

        f32x4 o[8] = {};
        float mrun = -INFINITY, lrun = 0.f;

        for (int ch = 0; ch <= qt; ++ch) {
            __syncthreads();
#pragma unroll
            for (int i = 0; i < 4; ++i) {
                int r = i * 16 + kr;
                GLDS(kgb + (size_t)(ch * 64 + r) * (KSTR * 2) + (kboff ^ ((r & 7) << 4)),
                     (char*)Ks + i * 4096 + tid * 16);
                int d = i * 32 + vr;
                GLDS(vgb + (size_t)d * (T_SEQ * 2) + (size_t)(ch * 64) * 2 + (vboff ^ ((d & 7) << 4)),
                     (char*)Vs + i * 4096 + tid * 16);
            }
            __syncthreads();

            // S^T = K @ Q^T : 4 key-blocks x 4 d-slices
            f32x4 st[4];
            __builtin_amdgcn_s_setprio(1);
#pragma unroll
            for (int kb = 0; kb < 4; ++kb) {
                f32x4 a = {};
#pragma unroll
                for (int ks = 0; ks < 4; ++ks) {
                    int row = kb * 16 + c16;
                    f16x8 kf = *(const f16x8*)((const char*)Ks + row * 256 +
                                               ((ks * 64 + g * 16) ^ ((row & 7) << 4)));
                    a = __builtin_amdgcn_mfma_f32_16x16x32_f16(kf, qf[ks], a, 0, 0, 0);
                }
                st[kb] = a;
            }
            __builtin_amdgcn_s_setprio(0);

            // scale + causal mask + online softmax (col q = c16 is lane-local)
            float p[16];
            float cmax = -INFINITY;
            const bool diag = (ch == qt);
#pragma unroll
            for (int kb = 0; kb < 4; ++kb)
#pragma unroll
                for (int r = 0; r < 4; ++r) {
                    float s = st[kb][r] * SCALE;
                    if (diag) {
                        int key = ch * 64 + kb * 16 + g * 4 + r;
                        if (key > qrow) s = -INFINITY;
                    }
                    p[kb * 4 + r] = s;
                    cmax = fmaxf(cmax, s);
                }
            cmax = fmaxf(cmax, __shfl_xor(cmax, 16));
            cmax = fmaxf(cmax, __shfl_xor(cmax, 32));

            // T13 defer-max: skip rescale while max grows < 8 (wave-uniform)
            float muse;
            if (__all(cmax <= mrun + 8.f)) {
                muse = mrun;
            } else {
                float mnew = fmaxf(mrun, cmax);
                float corr = __expf(mrun - mnew);
                lrun *= corr;
#pragma unroll
                for (int mb = 0; mb < 8; ++mb) o[mb] *= corr;
                mrun = mnew;
                muse = mnew;
            }
            float psum = 0.f;
#pragma unroll
            for (int i = 0; i < 16; ++i) { float e = __expf(p[i] - muse); p[i] = e; psum += e; }
            psum += __shfl_xor(psum, 16);
            psum += __shfl_xor(psum, 32);
            lrun += psum;

            // P -> per-wave LDS: row=q (c16), cols=keys
            f16* pw = Ps[w] + c16 * 72;
#pragma unroll
            for (int kb = 0; kb < 4; ++kb) {
                f16x4 q4 = {(f16)p[kb * 4], (f16)p[kb * 4 + 1], (f16)p[kb * 4 + 2], (f16)p[kb * 4 + 3]};
                *(f16x4*)(pw + kb * 16 + g * 4) = q4;
            }

            // O^T += Vt @ P^T : 8 d-blocks x 2 key-slices
            __builtin_amdgcn_s_setprio(1);
#pragma unroll
            for (int ks2 = 0; ks2 < 2; ++ks2) {
                f16x8 pf = *(const f16x8*)(Ps[w] + c16 * 72 + ks2 * 32 + g * 8);
#pragma unroll
                for (int mb = 0; mb < 8; ++mb) {
                    int row = mb * 16 + c16;
                    f16x8 vf = *(const f16x8*)((const char*)Vs + row * 128 +
                                               ((ks2 * 64 + g * 16) ^ ((row & 7) << 4)));
                    o[mb] = __builtin_amdgcn_mfma_f32_16x16x32_f16(vf, pf, o[mb], 0, 0, 0);
                }
            }
            __builtin_amdgcn_s_setprio(0);
        }

        float invl = 1.f / lrun;
        f16* ob = outh + (size_t)qrow * QCOLS + h * HD;
#pragma unroll
        for (int mb = 0; mb < 8; ++mb) {
            f16x4 v = {(f16)(o[mb][0] * invl), (f16)(o[mb][1] * invl),
                       (f16)(o[mb][2] * invl), (f16)(o[mb][3] * invl)};
            *(f16x4*)(ob + mb * 16 + g * 4) = v;
        }
    }
}

// ---------------- host launch ----------------
// Workspace (77 MB high-water; round-0 proved ws_size >= 81 MB):
//   [0,1) cos/sin  [1,17) xh (->atth)  [17,33) qh  [33,41) kvh
//   [41,53) wkvT (dead after QKV GEMM) / [41,73) woT (after attn)  [73,77) vtb
// wqT (32 MB) lives in d_out — dead before the out-GEMM overwrites d_out.
extern "C" void kernel_launch(void* const* d_in, const int* in_sizes, int n_in,
                              void* d_out, int out_size, void* d_ws, size_t ws_size,
                              hipStream_t stream) {
    const float* x  = (const float*)d_in[0];
    const float* wq = (const float*)d_in[1];
    const float* wk = (const float*)d_in[2];
    const float* wv = (const float*)d_in[3];
    const float* wo = (const float*)d_in[4];
    float* out = (float*)d_out;

    char* ws = (char*)d_ws;
    const size_t MB = 1024ULL * 1024ULL;
    float* cosT = (float*)(ws);
    float* sinT = (float*)(ws + 512 * 1024ULL);
    f16* xh   = (f16*)(ws + 1 * MB);
    f16* atth = xh;  // alias: xh dead after QKV GEMM
    f16* qh   = (f16*)(ws + 17 * MB);
    f16* kvh  = (f16*)(ws + 33 * MB);
    f16* wkvT = (f16*)(ws + 41 * MB);   // [2048][4096] f16 = 16 MB
    f16* woT  = (f16*)(ws + 41 * MB);   // [4096][4096] f16 = 32 MB (after attn)
    f16* vtb  = (f16*)(ws + 73 * MB);
    f16* wqT  = (f16*)d_out;            // 32 MB scratch, dead before out-GEMM

    rope_table<<<dim3((T_SEQ * 64 + 255) / 256), dim3(256), 0, stream>>>(cosT, sinT);
    convert_f32_f16<<<dim3(T_SEQ * HID / 8 / 256), dim3(256), 0, stream>>>(x, xh, T_SEQ * HID / 8);

    // transpose weights: wq -> wqT (d_out), wk|wv -> wkvT
    transpose_f32_to_f16<<<dim3(QCOLS / 64, HID / 64), dim3(256), 0, stream>>>(wq, wqT, HID, QCOLS);
    transpose_f32_to_f16<<<dim3(KCOLS / 64, HID / 64), dim3(256), 0, stream>>>(wk, wkvT, HID, KCOLS);
    transpose_f32_to_f16<<<dim3(KCOLS / 64, HID / 64), dim3(256), 0, stream>>>(
        wv, wkvT + (size_t)KCOLS * HID, HID, KCOLS);

    // merged Q|K|V GEMM: one 768-block launch (N = 4096 | 2048)
    gemm_qkv<<<dim3(NTOT / 128, T_SEQ / 128), dim3(256), 0, stream>>>(
        xh, wqT, wkvT, qh, kvh, HID);

    // RoPE on K only (Q fused into attn)
    rope_apply_f16<<<dim3(T_SEQ * NKV * 64 / 256), dim3(256), 0, stream>>>(
        kvh, cosT, sinT, NKV, KSTR);

    // vtb[d][t] = V^T from kvh cols 1024..2047
    transpose_f16<<<dim3(KCOLS / 64, T_SEQ / 64), dim3(256), 0, stream>>>(
        kvh + KCOLS, vtb, T_SEQ, KSTR);

    attn_f16<<<dim3(16, NH), dim3(256), 0, stream>>>(qh, kvh, vtb, cosT, sinT, atth);

    // out = atth @ wo
    transpose_f32_to_f16<<<dim3(HID / 64, QCOLS / 64), dim3(256), 0, stream>>>(wo, woT, QCOLS, HID);
    gemm_f16<float><<<dim3(HID / 128, T_SEQ / 128), dim3(256), 0, stream>>>(
        atth, woT, out, T_SEQ, HID, QCOLS);
}